// Round 5
// baseline (1113.760 us; speedup 1.0000x reference)
//
#include <hip/hip_runtime.h>

#define HID 16
#define ODIM 64
#define IDIM 512
#define BKB 8          // bucket = 256 nodes (dst >> 8)
#define BKS 256
#define PTILE 8192     // edges per partition tile
#define PITER 16       // PTILE / 512
#define PAD 16         // ints per padded counter slot (64 B line)
#define APAD 17        // padded LDS acc row stride (floats) -> conflict-free-ish

// ---------------------------------------------------- bucket histogram (dst>>8)
__global__ __launch_bounds__(512) void k_bhist(const int* __restrict__ dst,
                                               int* __restrict__ bcnt, int ne, int nbk) {
    __shared__ int h[512];
    int t = threadIdx.x;
    h[t] = 0;
    __syncthreads();
    int stride = gridDim.x * 512;
    for (int e = blockIdx.x * 512 + t; e < ne; e += stride)
        atomicAdd(&h[dst[e] >> BKB], 1);
    __syncthreads();
    if (t < nbk && h[t]) atomicAdd(&bcnt[t * PAD], h[t]);
}

// inclusive block scan (512 thr) via wave shuffles; 2 barriers.
__device__ __forceinline__ int wave_scan_block(int v, int t, int* wsum) {
    int lane = t & 63, w = t >> 6;
    int x = v;
#pragma unroll
    for (int off = 1; off < 64; off <<= 1) {
        int y = __shfl_up(x, off, 64);
        if (lane >= off) x += y;
    }
    if (lane == 63) wsum[w] = x;
    __syncthreads();
    if (w == 0) {
        int s = (lane < 8) ? wsum[lane] : 0;
#pragma unroll
        for (int off = 1; off < 8; off <<= 1) {
            int y = __shfl_up(s, off, 64);
            if (lane >= off) s += y;
        }
        if (lane < 8) wsum[lane] = s;
    }
    __syncthreads();
    return x + (w ? wsum[w - 1] : 0);
}

// ------------------------------------------------- scan bucket counts
__global__ __launch_bounds__(512) void k_bscan(const int* __restrict__ bcnt,
                                               int* __restrict__ bbase,
                                               int* __restrict__ bcur, int nbk) {
    __shared__ int wsum[8];
    int t = threadIdx.x;
    int v = (t < nbk) ? bcnt[t * PAD] : 0;
    int inc = wave_scan_block(v, t, wsum);
    if (t < nbk) { int b = inc - v; bbase[t] = b; bcur[t * PAD] = b; }
}

// ------------------------------------- partition edges into buckets (direct store)
// packed entry: (src << 8) | (dst & 255);  src < 2^17 so fits u32.
// No tile-local ordering needed -> no scan, no LDS staging: store to base[b]+r.
// Active write window per tile ~391 buckets x ~84 B = ~33 KB of L2 lines that get
// fully covered across the tile -> no HBM write amplification (unlike R2's k_scat).
__global__ __launch_bounds__(512) void k_part(const int* __restrict__ src,
                                              const int* __restrict__ dst,
                                              int* __restrict__ bcur,
                                              unsigned int* __restrict__ ebuf, int ne) {
    __shared__ int h[512], base[512], lcur[512];
    int e0 = blockIdx.x * PTILE;
    int m = ne - e0; if (m > PTILE) m = PTILE;
    int t = threadIdx.x;
    h[t] = 0;
    __syncthreads();
    int dv[PITER];
#pragma unroll
    for (int it = 0; it < PITER; ++it) {
        int k = t + it * 512;
        int d = 0;
        if (k < m) { d = dst[e0 + k]; atomicAdd(&h[d >> BKB], 1); }
        dv[it] = d;
    }
    __syncthreads();
    int hv = h[t];
    base[t] = hv ? atomicAdd(&bcur[t * PAD], hv) : 0;
    lcur[t] = 0;
    __syncthreads();
#pragma unroll
    for (int it = 0; it < PITER; ++it) {
        int k = t + it * 512;
        if (k < m) {
            int d = dv[it];
            int b = d >> BKB;
            int r = atomicAdd(&lcur[b], 1);
            ebuf[base[b] + r] =
                ((unsigned int)src[e0 + k] << BKB) | (unsigned int)(d & (BKS - 1));
        }
    }
}

// ------------------------------------------- per-bucket degree (dstlocal hist)
__global__ __launch_bounds__(512) void k_cnt(const int* __restrict__ bbase,
                                             const int* __restrict__ bcnt,
                                             const unsigned int* __restrict__ ebuf,
                                             int* __restrict__ cnt, int n) {
    __shared__ int h[256];
    int bk = blockIdx.x;
    int ebase = bbase[bk];
    int ecnt = bcnt[bk * PAD];
    int t = threadIdx.x;
    if (t < 256) h[t] = 0;
    __syncthreads();
    for (int k = t; k < ecnt; k += 512) atomicAdd(&h[ebuf[ebase + k] & (BKS - 1)], 1);
    __syncthreads();
    int node = (bk << BKB) + t;
    if (t < 256 && node < n) cnt[node] = h[t];
}

// ------------------------------------------------- layer1 projection: X @ W1
// W1 read with wave-uniform float4 indices -> s_load broadcast (scalar pipe).
__device__ __forceinline__ void fmaq(float4& a, float s, float4 w) {
    a.x = fmaf(s, w.x, a.x);
    a.y = fmaf(s, w.y, a.y);
    a.z = fmaf(s, w.z, a.z);
    a.w = fmaf(s, w.w, a.w);
}

__global__ __launch_bounds__(256) void k_proj1(const float* __restrict__ X,
                                               const float* __restrict__ W1,
                                               const int* __restrict__ cnt,
                                               float* __restrict__ hs1, int n) {
    int i = blockIdx.x * 256 + threadIdx.x;
    if (i >= n) return;

    const float4* __restrict__ xr = (const float4*)(X + (size_t)i * IDIM);
    const float4* __restrict__ W4 = (const float4*)W1;  // row k = W4[k*4 .. k*4+3]
    float4 a0 = make_float4(0.f, 0.f, 0.f, 0.f), a1 = a0, a2 = a0, a3 = a0;

#pragma unroll 4
    for (int k4 = 0; k4 < IDIM / 4; ++k4) {
        float4 x = xr[k4];
        const float4* w = W4 + k4 * 16;   // 4 rows x 4 float4, wave-uniform address
        fmaq(a0, x.x, w[0]);  fmaq(a1, x.x, w[1]);  fmaq(a2, x.x, w[2]);  fmaq(a3, x.x, w[3]);
        fmaq(a0, x.y, w[4]);  fmaq(a1, x.y, w[5]);  fmaq(a2, x.y, w[6]);  fmaq(a3, x.y, w[7]);
        fmaq(a0, x.z, w[8]);  fmaq(a1, x.z, w[9]);  fmaq(a2, x.z, w[10]); fmaq(a3, x.z, w[11]);
        fmaq(a0, x.w, w[12]); fmaq(a1, x.w, w[13]); fmaq(a2, x.w, w[14]); fmaq(a3, x.w, w[15]);
    }

    float di = rsqrtf((float)(cnt[i] + 1));
    a0.x *= di; a0.y *= di; a0.z *= di; a0.w *= di;
    a1.x *= di; a1.y *= di; a1.z *= di; a1.w *= di;
    a2.x *= di; a2.y *= di; a2.z *= di; a2.w *= di;
    a3.x *= di; a3.y *= di; a3.z *= di; a3.w *= di;
    float4* h4 = (float4*)(hs1 + (size_t)i * HID);
    h4[0] = a0; h4[1] = a1; h4[2] = a2; h4[3] = a3;
}

// --------------------- edge-parallel bucket aggregation in LDS (ds_add_f32)
// One block per 256-node bucket: acc[dl][j] initialized with self-loop rows,
// then each thread streams bucket edges, gathers the 64 B h-row of src and
// LDS-atomic-adds into the dst-local row. APAD=17: bank(dl*17+j) collides only
// when dl == dl (mod 32) -> ~2-way (free class). MODE 1 fuses layer-1 finalize.
template <int MODE>
__global__ __launch_bounds__(512) void k_agg(const int* __restrict__ bbase,
                                             const int* __restrict__ bcnt,
                                             const unsigned int* __restrict__ ebuf,
                                             const float* __restrict__ hs,
                                             const int* __restrict__ cnt,
                                             const float* __restrict__ b1,
                                             float* __restrict__ outb, int n) {
    __shared__ float acc[BKS * APAD];
    int bk = blockIdx.x;
    int node0 = bk << BKB;
    int ebase = bbase[bk];
    int ecnt = bcnt[bk * PAD];
    int t = threadIdx.x;

    for (int u = t; u < BKS * HID; u += 512) {       // self-loop init, coalesced
        int dl = u >> 4, j = u & 15;
        int node = node0 + dl;
        acc[dl * APAD + j] = (node < n) ? hs[(size_t)node * HID + j] : 0.f;
    }
    __syncthreads();

    int k = t;
    for (; k + 512 < ecnt; k += 1024) {              // 2 edges in flight per lane
        unsigned int p0 = ebuf[ebase + k];
        unsigned int p1 = ebuf[ebase + k + 512];
        const float4* r0 = (const float4*)(hs + (size_t)(p0 >> BKB) * HID);
        const float4* r1 = (const float4*)(hs + (size_t)(p1 >> BKB) * HID);
        float4 a0 = r0[0], a1 = r0[1], a2 = r0[2], a3 = r0[3];
        float4 c0 = r1[0], c1 = r1[1], c2 = r1[2], c3 = r1[3];
        float* d0 = &acc[(int)(p0 & (BKS - 1)) * APAD];
        float* d1 = &acc[(int)(p1 & (BKS - 1)) * APAD];
        atomicAdd(&d0[0], a0.x);  atomicAdd(&d0[1], a0.y);  atomicAdd(&d0[2], a0.z);  atomicAdd(&d0[3], a0.w);
        atomicAdd(&d0[4], a1.x);  atomicAdd(&d0[5], a1.y);  atomicAdd(&d0[6], a1.z);  atomicAdd(&d0[7], a1.w);
        atomicAdd(&d0[8], a2.x);  atomicAdd(&d0[9], a2.y);  atomicAdd(&d0[10], a2.z); atomicAdd(&d0[11], a2.w);
        atomicAdd(&d0[12], a3.x); atomicAdd(&d0[13], a3.y); atomicAdd(&d0[14], a3.z); atomicAdd(&d0[15], a3.w);
        atomicAdd(&d1[0], c0.x);  atomicAdd(&d1[1], c0.y);  atomicAdd(&d1[2], c0.z);  atomicAdd(&d1[3], c0.w);
        atomicAdd(&d1[4], c1.x);  atomicAdd(&d1[5], c1.y);  atomicAdd(&d1[6], c1.z);  atomicAdd(&d1[7], c1.w);
        atomicAdd(&d1[8], c2.x);  atomicAdd(&d1[9], c2.y);  atomicAdd(&d1[10], c2.z); atomicAdd(&d1[11], c2.w);
        atomicAdd(&d1[12], c3.x); atomicAdd(&d1[13], c3.y); atomicAdd(&d1[14], c3.z); atomicAdd(&d1[15], c3.w);
    }
    if (k < ecnt) {                                  // at most one tail edge/lane
        unsigned int p0 = ebuf[ebase + k];
        const float4* r0 = (const float4*)(hs + (size_t)(p0 >> BKB) * HID);
        float4 a0 = r0[0], a1 = r0[1], a2 = r0[2], a3 = r0[3];
        float* d0 = &acc[(int)(p0 & (BKS - 1)) * APAD];
        atomicAdd(&d0[0], a0.x);  atomicAdd(&d0[1], a0.y);  atomicAdd(&d0[2], a0.z);  atomicAdd(&d0[3], a0.w);
        atomicAdd(&d0[4], a1.x);  atomicAdd(&d0[5], a1.y);  atomicAdd(&d0[6], a1.z);  atomicAdd(&d0[7], a1.w);
        atomicAdd(&d0[8], a2.x);  atomicAdd(&d0[9], a2.y);  atomicAdd(&d0[10], a2.z); atomicAdd(&d0[11], a2.w);
        atomicAdd(&d0[12], a3.x); atomicAdd(&d0[13], a3.y); atomicAdd(&d0[14], a3.z); atomicAdd(&d0[15], a3.w);
    }
    __syncthreads();

    for (int u = t; u < BKS * HID; u += 512) {       // epilogue, coalesced
        int dl = u >> 4, j = u & 15;
        int node = node0 + dl;
        if (node < n) {
            float v = acc[dl * APAD + j];
            if (MODE == 1) {                          // h2 = relu(di*agg + b1) * di
                float di = rsqrtf((float)(cnt[node] + 1));
                v = fmaxf(fmaf(di, v, b1[j]), 0.f) * di;
            }
            outb[(size_t)node * HID + j] = v;
        }
    }
}

// ----------------------------------------------- output projection g @ W2 + b
// Each thread owns ONE W2 column (16 VGPRs), amortized over 4 nodes.
__global__ __launch_bounds__(256) void k_out(const int* __restrict__ cnt,
                                             const float* __restrict__ agg2,
                                             const float* __restrict__ W2,
                                             const float* __restrict__ b2,
                                             float* __restrict__ out, int n) {
    __shared__ float Ws[HID * ODIM];
    __shared__ float bs[ODIM];
    int t = threadIdx.x;
    for (int u = t; u < HID * ODIM; u += 256) Ws[u] = W2[u];
    if (t < ODIM) bs[t] = b2[t];
    __syncthreads();

    int j = t & 63;            // output column
    int slot = t >> 6;         // 0..3 (== wave id)
    int i0 = blockIdx.x * 16 + slot * 4;

    float wc[HID];
#pragma unroll
    for (int k = 0; k < HID; ++k) wc[k] = Ws[k * ODIM + j];
    float bj = bs[j];

    const float4* g4 = (const float4*)agg2;
#pragma unroll
    for (int u = 0; u < 4; ++u) {
        int i = i0 + u;
        if (i < n) {
            float4 g0 = g4[(size_t)i * 4 + 0];
            float4 g1 = g4[(size_t)i * 4 + 1];
            float4 g2 = g4[(size_t)i * 4 + 2];
            float4 g3 = g4[(size_t)i * 4 + 3];
            float acc = g0.x * wc[0]  + g0.y * wc[1]  + g0.z * wc[2]  + g0.w * wc[3]
                      + g1.x * wc[4]  + g1.y * wc[5]  + g1.z * wc[6]  + g1.w * wc[7]
                      + g2.x * wc[8]  + g2.y * wc[9]  + g2.z * wc[10] + g2.w * wc[11]
                      + g3.x * wc[12] + g3.y * wc[13] + g3.z * wc[14] + g3.w * wc[15];
            float di = rsqrtf((float)(cnt[i] + 1));
            out[(size_t)i * ODIM + j] = fmaf(di, acc, bj);
        }
    }
}

// ---------------------------------------------------------------------- launch
extern "C" void kernel_launch(void* const* d_in, const int* in_sizes, int n_in,
                              void* d_out, int out_size, void* d_ws, size_t ws_size,
                              hipStream_t stream) {
    const int* E = (const int*)d_in[1];
    const float* X = (const float*)d_in[2];
    const float* W1 = (const float*)d_in[3];
    const float* b1 = (const float*)d_in[4];
    const float* W2 = (const float*)d_in[5];
    const float* b2 = (const float*)d_in[6];
    float* out = (float*)d_out;

    const int n = in_sizes[0];       // 100000
    const int ne = in_sizes[1] / 2;  // 3200000
    const int* src = E;
    const int* dst = E + ne;
    const int nbk = (n + BKS - 1) >> BKB;  // 391

    // workspace layout (bytes):
    //   bcnt(pad) @ 0     (25 KB)
    //   bbase     @ 32 KB (2 KB)
    //   bcur(pad) @ 64 KB (25 KB)
    //   cnt       @ 1 MB  (400 KB)
    //   ebuf      @ 3 MB  (12.8 MB)  [live through both k_agg calls]
    //   B1        @ 17 MB (6.4 MB)
    //   B2        @ 24 MB (6.4 MB)   -> total 30.4 MB
    char* ws = (char*)d_ws;
    int* bcnt = (int*)ws;
    int* bbase = (int*)(ws + (32u << 10));
    int* bcur = (int*)(ws + (64u << 10));
    int* cnt = (int*)(ws + (1u << 20));
    unsigned int* ebuf = (unsigned int*)(ws + (3u << 20));
    float* B1 = (float*)(ws + (17u << 20));
    float* B2 = (float*)(ws + (24u << 20));

    hipMemsetAsync(bcnt, 0, nbk * PAD * sizeof(int), stream);
    k_bhist<<<256, 512, 0, stream>>>(dst, bcnt, ne, nbk);
    k_bscan<<<1, 512, 0, stream>>>(bcnt, bbase, bcur, nbk);
    k_part<<<(ne + PTILE - 1) / PTILE, 512, 0, stream>>>(src, dst, bcur, ebuf, ne);
    k_cnt<<<nbk, 512, 0, stream>>>(bbase, bcnt, ebuf, cnt, n);

    k_proj1<<<(n + 255) / 256, 256, 0, stream>>>(X, W1, cnt, B1, n);
    k_agg<1><<<nbk, 512, 0, stream>>>(bbase, bcnt, ebuf, B1, cnt, b1, B2, n);
    k_agg<0><<<nbk, 512, 0, stream>>>(bbase, bcnt, ebuf, B2, cnt, b1, B1, n);
    k_out<<<(n + 15) / 16, 256, 0, stream>>>(cnt, B1, W2, b2, out, n);
}

// Round 6
// 497.340 us; speedup vs baseline: 2.2394x; 2.2394x over previous
//
#include <hip/hip_runtime.h>

#define HID 16
#define ODIM 64
#define IDIM 512
#define BKB 8          // bucket = 256 nodes (dst >> 8)
#define BKS 256
#define PTILE 8192     // edges per partition tile
#define PITER 16       // PTILE / 512
#define PAD 16         // ints per padded counter slot (64 B line)

// inclusive block scan (blockDim.x == 512) via wave shuffles; 2 barriers total.
__device__ __forceinline__ int wave_scan_block(int v, int t, int* wsum) {
    int lane = t & 63, w = t >> 6;
    int x = v;
#pragma unroll
    for (int off = 1; off < 64; off <<= 1) {
        int y = __shfl_up(x, off, 64);
        if (lane >= off) x += y;
    }
    if (lane == 63) wsum[w] = x;
    __syncthreads();
    if (w == 0) {
        int s = (lane < 8) ? wsum[lane] : 0;
#pragma unroll
        for (int off = 1; off < 8; off <<= 1) {
            int y = __shfl_up(s, off, 64);
            if (lane >= off) s += y;
        }
        if (lane < 8) wsum[lane] = s;
    }
    __syncthreads();
    return x + (w ? wsum[w - 1] : 0);
}

// ---------------------------------------------------- bucket histogram (dst>>8)
__global__ __launch_bounds__(512) void k_bhist(const int* __restrict__ dst,
                                               int* __restrict__ bcnt, int ne, int nbk) {
    __shared__ int h[512];
    int t = threadIdx.x;
    h[t] = 0;
    __syncthreads();
    int stride = gridDim.x * 512;
    for (int e = blockIdx.x * 512 + t; e < ne; e += stride)
        atomicAdd(&h[dst[e] >> BKB], 1);
    __syncthreads();
    if (t < nbk && h[t]) atomicAdd(&bcnt[t * PAD], h[t]);
}

// ------------------------------------------------- scan bucket counts (wave scan)
__global__ __launch_bounds__(512) void k_bscan(const int* __restrict__ bcnt,
                                               int* __restrict__ bbase,
                                               int* __restrict__ bcur, int nbk) {
    __shared__ int wsum[8];
    int t = threadIdx.x;
    int v = (t < nbk) ? bcnt[t * PAD] : 0;
    int inc = wave_scan_block(v, t, wsum);
    if (t < nbk) { int b = inc - v; bbase[t] = b; bcur[t * PAD] = b; }
}

// ------------------------------------- partition edges into buckets (staged LDS)
// packed entry: (src << 8) | (dst & 255);  src < 2^17 so fits u32.
__global__ __launch_bounds__(512) void k_part(const int* __restrict__ src,
                                              const int* __restrict__ dst,
                                              int* __restrict__ bcur,
                                              unsigned int* __restrict__ ebuf, int ne) {
    __shared__ int h[512], sc[512], base[512], lcur[512], wsum[8];
    __shared__ unsigned int sval[PTILE];
    __shared__ int saddr[PTILE];
    int e0 = blockIdx.x * PTILE;
    int m = ne - e0; if (m > PTILE) m = PTILE;
    int t = threadIdx.x;
    h[t] = 0;
    __syncthreads();
    int dv[PITER];
#pragma unroll
    for (int it = 0; it < PITER; ++it) {
        int k = t + it * 512;
        int d = 0;
        if (k < m) { d = dst[e0 + k]; atomicAdd(&h[d >> BKB], 1); }
        dv[it] = d;
    }
    __syncthreads();
    int hv = h[t];
    int inc = wave_scan_block(hv, t, wsum);
    sc[t] = inc;
    base[t] = hv ? atomicAdd(&bcur[t * PAD], hv) : 0;
    lcur[t] = 0;
    __syncthreads();
#pragma unroll
    for (int it = 0; it < PITER; ++it) {
        int k = t + it * 512;
        if (k < m) {
            int d = dv[it];
            int b = d >> BKB;
            int r = atomicAdd(&lcur[b], 1);
            int slot = sc[b] - h[b] + r;              // tile-local bucket run
            sval[slot] = ((unsigned int)src[e0 + k] << BKB) | (unsigned int)(d & (BKS - 1));
            saddr[slot] = base[b] + r;                // global dest (bucket-grouped)
        }
    }
    __syncthreads();
#pragma unroll
    for (int it = 0; it < PITER; ++it) {
        int k = t + it * 512;
        if (k < m) ebuf[saddr[k]] = sval[k];
    }
}

// ------------------- per-bucket CSR build: cnt, row_start, csr_src (direct scatter)
// Block's csr_src region is a contiguous ~32KB -> stays hot in its XCD L2.
__global__ __launch_bounds__(512) void k_csr(const int* __restrict__ bbase,
                                             const int* __restrict__ bcnt,
                                             const unsigned int* __restrict__ ebuf,
                                             int* __restrict__ cnt,
                                             int* __restrict__ row_start,
                                             int* __restrict__ csr_src, int n) {
    __shared__ int h[256], sc[256], lc[256], wsum[8];
    int bk = blockIdx.x;
    int node0 = bk << BKB;
    int ebase = bbase[bk];
    int ecnt = bcnt[bk * PAD];
    int t = threadIdx.x;
    if (t < 256) { h[t] = 0; lc[t] = 0; }
    __syncthreads();
    for (int k = t; k < ecnt; k += 512) atomicAdd(&h[ebuf[ebase + k] & (BKS - 1)], 1);
    __syncthreads();
    int hv = (t < 256) ? h[t] : 0;
    int inc = wave_scan_block(hv, t, wsum);
    if (t < 256) {
        sc[t] = inc;
        int node = node0 + t;
        if (node < n) { cnt[node] = hv; row_start[node] = ebase + inc - hv; }
    }
    __syncthreads();
    for (int k = t; k < ecnt; k += 512) {
        unsigned int p = ebuf[ebase + k];
        int dl = p & (BKS - 1);
        int r = atomicAdd(&lc[dl], 1);
        csr_src[ebase + sc[dl] - h[dl] + r] = (int)(p >> BKB);
    }
}

// ------------------------------------------------- layer1 projection: X @ W1
// W1 read with wave-uniform float4 indices -> s_load broadcast (scalar pipe).
__device__ __forceinline__ void fmaq(float4& a, float s, float4 w) {
    a.x = fmaf(s, w.x, a.x);
    a.y = fmaf(s, w.y, a.y);
    a.z = fmaf(s, w.z, a.z);
    a.w = fmaf(s, w.w, a.w);
}

__global__ __launch_bounds__(256) void k_proj1(const float* __restrict__ X,
                                               const float* __restrict__ W1,
                                               const int* __restrict__ cnt,
                                               float* __restrict__ hs1, int n) {
    int i = blockIdx.x * 256 + threadIdx.x;
    if (i >= n) return;

    const float4* __restrict__ xr = (const float4*)(X + (size_t)i * IDIM);
    const float4* __restrict__ W4 = (const float4*)W1;  // row k = W4[k*4 .. k*4+3]
    float4 a0 = make_float4(0.f, 0.f, 0.f, 0.f), a1 = a0, a2 = a0, a3 = a0;

#pragma unroll 4
    for (int k4 = 0; k4 < IDIM / 4; ++k4) {
        float4 x = xr[k4];
        const float4* w = W4 + k4 * 16;   // 4 rows x 4 float4, wave-uniform address
        fmaq(a0, x.x, w[0]);  fmaq(a1, x.x, w[1]);  fmaq(a2, x.x, w[2]);  fmaq(a3, x.x, w[3]);
        fmaq(a0, x.y, w[4]);  fmaq(a1, x.y, w[5]);  fmaq(a2, x.y, w[6]);  fmaq(a3, x.y, w[7]);
        fmaq(a0, x.z, w[8]);  fmaq(a1, x.z, w[9]);  fmaq(a2, x.z, w[10]); fmaq(a3, x.z, w[11]);
        fmaq(a0, x.w, w[12]); fmaq(a1, x.w, w[13]); fmaq(a2, x.w, w[14]); fmaq(a3, x.w, w[15]);
    }

    float di = rsqrtf((float)(cnt[i] + 1));
    a0.x *= di; a0.y *= di; a0.z *= di; a0.w *= di;
    a1.x *= di; a1.y *= di; a1.z *= di; a1.w *= di;
    a2.x *= di; a2.y *= di; a2.z *= di; a2.w *= di;
    a3.x *= di; a3.y *= di; a3.z *= di; a3.w *= di;
    float4* h4 = (float4*)(hs1 + (size_t)i * HID);
    h4[0] = a0; h4[1] = a1; h4[2] = a2; h4[3] = a3;
}

// ------------------------------------------- atomic-free aggregation via CSR
// R5 measured the random-gather regime as LATENCY-bound (291 GB/s, VALU 0.5%):
// so expose 16 gathers in flight per wait with 4 independent accumulator chains.
__device__ __forceinline__ void acc4(float4& a, float4 v) {
    a.x += v.x; a.y += v.y; a.z += v.z; a.w += v.w;
}

__device__ __forceinline__ float4 gacc(int rs, int c, int q,
                                       const int* __restrict__ csr_src,
                                       const float4* __restrict__ h4,
                                       float4 acc) {
    float4 accB = make_float4(0.f, 0.f, 0.f, 0.f);
    float4 accC = accB, accD = accB;
    int k = 0;
    int head = (-rs) & 3;            // peel to 16B-aligned csr_src
    if (head > c) head = c;
    for (; k < head; ++k)
        acc4(acc, h4[(size_t)csr_src[rs + k] * 4 + q]);
    for (; k + 15 < c; k += 16) {    // 16 gathers in flight
        int4 s0 = *(const int4*)(csr_src + rs + k);
        int4 s1 = *(const int4*)(csr_src + rs + k + 4);
        int4 s2 = *(const int4*)(csr_src + rs + k + 8);
        int4 s3 = *(const int4*)(csr_src + rs + k + 12);
        float4 v0 = h4[(size_t)s0.x * 4 + q];
        float4 v1 = h4[(size_t)s0.y * 4 + q];
        float4 v2 = h4[(size_t)s0.z * 4 + q];
        float4 v3 = h4[(size_t)s0.w * 4 + q];
        float4 v4 = h4[(size_t)s1.x * 4 + q];
        float4 v5 = h4[(size_t)s1.y * 4 + q];
        float4 v6 = h4[(size_t)s1.z * 4 + q];
        float4 v7 = h4[(size_t)s1.w * 4 + q];
        float4 v8 = h4[(size_t)s2.x * 4 + q];
        float4 v9 = h4[(size_t)s2.y * 4 + q];
        float4 va = h4[(size_t)s2.z * 4 + q];
        float4 vb = h4[(size_t)s2.w * 4 + q];
        float4 vc = h4[(size_t)s3.x * 4 + q];
        float4 vd = h4[(size_t)s3.y * 4 + q];
        float4 ve = h4[(size_t)s3.z * 4 + q];
        float4 vf = h4[(size_t)s3.w * 4 + q];
        acc4(acc, v0);  acc4(accB, v4);  acc4(accC, v8);  acc4(accD, vc);
        acc4(acc, v1);  acc4(accB, v5);  acc4(accC, v9);  acc4(accD, vd);
        acc4(acc, v2);  acc4(accB, v6);  acc4(accC, va);  acc4(accD, ve);
        acc4(acc, v3);  acc4(accB, v7);  acc4(accC, vb);  acc4(accD, vf);
    }
    for (; k + 3 < c; k += 4) {
        int4 s = *(const int4*)(csr_src + rs + k);
        acc4(acc, h4[(size_t)s.x * 4 + q]);
        acc4(accB, h4[(size_t)s.y * 4 + q]);
        acc4(accC, h4[(size_t)s.z * 4 + q]);
        acc4(accD, h4[(size_t)s.w * 4 + q]);
    }
    for (; k < c; ++k)
        acc4(acc, h4[(size_t)csr_src[rs + k] * 4 + q]);
    acc4(accB, accC);
    acc4(acc, accD);
    acc4(acc, accB);
    return acc;
}

// gather + fused layer-1 finalize: h2 = relu(di*agg + b1) * di
__global__ __launch_bounds__(256) void k_gather_mid(const int* __restrict__ row_start,
                                                    const int* __restrict__ cnt,
                                                    const int* __restrict__ csr_src,
                                                    const float* __restrict__ hs,
                                                    const float* __restrict__ b1,
                                                    float* __restrict__ outbuf, int n) {
    int tid = blockIdx.x * blockDim.x + threadIdx.x;
    int i = tid >> 2;
    int q = tid & 3;
    if (i >= n) return;
    const float4* h4 = (const float4*)hs;
    int rs = row_start[i];
    int c = cnt[i];
    float4 acc = gacc(rs, c, q, csr_src, h4, h4[(size_t)i * 4 + q]);  // self loop as init
    float di = rsqrtf((float)(c + 1));
    float4 b = ((const float4*)b1)[q];
    float4 r;
    r.x = fmaxf(fmaf(di, acc.x, b.x), 0.f) * di;
    r.y = fmaxf(fmaf(di, acc.y, b.y), 0.f) * di;
    r.z = fmaxf(fmaf(di, acc.z, b.z), 0.f) * di;
    r.w = fmaxf(fmaf(di, acc.w, b.w), 0.f) * di;
    ((float4*)outbuf)[(size_t)i * 4 + q] = r;
}

// plain gather (layer 2 aggregation)
__global__ __launch_bounds__(256) void k_gather(const int* __restrict__ row_start,
                                                const int* __restrict__ cnt,
                                                const int* __restrict__ csr_src,
                                                const float* __restrict__ hs,
                                                float* __restrict__ agg, int n) {
    int tid = blockIdx.x * blockDim.x + threadIdx.x;
    int i = tid >> 2;
    int q = tid & 3;
    if (i >= n) return;
    const float4* h4 = (const float4*)hs;
    int rs = row_start[i];
    int c = cnt[i];
    float4 acc = gacc(rs, c, q, csr_src, h4, h4[(size_t)i * 4 + q]);
    ((float4*)agg)[(size_t)i * 4 + q] = acc;
}

// ----------------------------------------------- output projection g @ W2 + b
// Each thread owns ONE W2 column (16 VGPRs), amortized over 4 nodes.
__global__ __launch_bounds__(256) void k_out(const int* __restrict__ cnt,
                                             const float* __restrict__ agg2,
                                             const float* __restrict__ W2,
                                             const float* __restrict__ b2,
                                             float* __restrict__ out, int n) {
    __shared__ float Ws[HID * ODIM];
    __shared__ float bs[ODIM];
    int t = threadIdx.x;
    for (int u = t; u < HID * ODIM; u += 256) Ws[u] = W2[u];
    if (t < ODIM) bs[t] = b2[t];
    __syncthreads();

    int j = t & 63;            // output column
    int slot = t >> 6;         // 0..3 (== wave id)
    int i0 = blockIdx.x * 16 + slot * 4;

    float wc[HID];
#pragma unroll
    for (int k = 0; k < HID; ++k) wc[k] = Ws[k * ODIM + j];
    float bj = bs[j];

    const float4* g4 = (const float4*)agg2;
#pragma unroll
    for (int u = 0; u < 4; ++u) {
        int i = i0 + u;
        if (i < n) {
            float4 g0 = g4[(size_t)i * 4 + 0];
            float4 g1 = g4[(size_t)i * 4 + 1];
            float4 g2 = g4[(size_t)i * 4 + 2];
            float4 g3 = g4[(size_t)i * 4 + 3];
            float acc = g0.x * wc[0]  + g0.y * wc[1]  + g0.z * wc[2]  + g0.w * wc[3]
                      + g1.x * wc[4]  + g1.y * wc[5]  + g1.z * wc[6]  + g1.w * wc[7]
                      + g2.x * wc[8]  + g2.y * wc[9]  + g2.z * wc[10] + g2.w * wc[11]
                      + g3.x * wc[12] + g3.y * wc[13] + g3.z * wc[14] + g3.w * wc[15];
            float di = rsqrtf((float)(cnt[i] + 1));
            out[(size_t)i * ODIM + j] = fmaf(di, acc, bj);
        }
    }
}

// ---------------------------------------------------------------------- launch
extern "C" void kernel_launch(void* const* d_in, const int* in_sizes, int n_in,
                              void* d_out, int out_size, void* d_ws, size_t ws_size,
                              hipStream_t stream) {
    const int* E = (const int*)d_in[1];
    const float* X = (const float*)d_in[2];
    const float* W1 = (const float*)d_in[3];
    const float* b1 = (const float*)d_in[4];
    const float* W2 = (const float*)d_in[5];
    const float* b2 = (const float*)d_in[6];
    float* out = (float*)d_out;

    const int n = in_sizes[0];       // 100000
    const int ne = in_sizes[1] / 2;  // 3200000
    const int* src = E;
    const int* dst = E + ne;
    const int nbk = (n + BKS - 1) >> BKB;  // 391

    // workspace layout (bytes):
    //   bcnt(pad) @ 0     (25 KB)
    //   bbase     @ 32 KB (2 KB)
    //   bcur(pad) @ 64 KB (25 KB)
    //   cnt       @ 1 MB  (400 KB)
    //   row_start @ 2 MB  (400 KB)
    //   ebuf      @ 3 MB  (12.8 MB)  [dead after k_csr; B1/B2 alias it]
    //   B1        @ 3 MB  (6.4 MB)
    //   B2        @ 10 MB (6.4 MB)
    //   csr_src   @ 17 MB (12.8 MB)   -> total 29.8 MB
    char* ws = (char*)d_ws;
    int* bcnt = (int*)ws;
    int* bbase = (int*)(ws + (32u << 10));
    int* bcur = (int*)(ws + (64u << 10));
    int* cnt = (int*)(ws + (1u << 20));
    int* row_start = (int*)(ws + (2u << 20));
    unsigned int* ebuf = (unsigned int*)(ws + (3u << 20));
    float* B1 = (float*)(ws + (3u << 20));
    float* B2 = (float*)(ws + (10u << 20));
    int* csr_src = (int*)(ws + (17u << 20));

    hipMemsetAsync(bcnt, 0, nbk * PAD * sizeof(int), stream);
    k_bhist<<<256, 512, 0, stream>>>(dst, bcnt, ne, nbk);
    k_bscan<<<1, 512, 0, stream>>>(bcnt, bbase, bcur, nbk);
    k_part<<<(ne + PTILE - 1) / PTILE, 512, 0, stream>>>(src, dst, bcur, ebuf, ne);
    k_csr<<<nbk, 512, 0, stream>>>(bbase, bcnt, ebuf, cnt, row_start, csr_src, n);

    k_proj1<<<(n + 255) / 256, 256, 0, stream>>>(X, W1, cnt, B1, n);
    k_gather_mid<<<(n * 4 + 255) / 256, 256, 0, stream>>>(row_start, cnt, csr_src, B1, b1, B2, n);
    k_gather<<<(n * 4 + 255) / 256, 256, 0, stream>>>(row_start, cnt, csr_src, B2, B1, n);
    k_out<<<(n + 15) / 16, 256, 0, stream>>>(cnt, B1, W2, b2, out, n);
}